// Round 4
// baseline (762.684 us; speedup 1.0000x reference)
//
#include <hip/hip_runtime.h>

// MQA forward, MI355X gfx950. B=4 H=32 S=2048 D=128, fp32 I/O, bf16 MFMA.
// R4: P never touches LDS. Swapped QK^T leaves P lane-local (q = lane&15);
// a 16-shfl register exchange rearranges P into the PV B-operand fragment,
// and PV runs operand-swapped: oacc = mfma(V^T-frag as A, P-frag as B),
// giving O[d][q=l15] so rescale + 1/l are lane-local and the epilogue is
// 8 x float4 stores. Removes per tile: 16 conflicted ds_write_u16,
// 2 ds_read_b128, lgkmcnt(0) + sched_barrier(0) serialization, 8KB LDS.
// Staging / QK^T / softmax identical to R3 (proven).

#define B_SZ 4
#define H_SZ 32
#define S_SZ 2048
#define D_SZ 128
#define QBLK 64
#define KBLK 64
// (1/sqrt(128)) * log2(e): scores live in log2 domain
#define QSCALE 0.12751743f
#define DEFER_THR 8.0f

typedef __attribute__((ext_vector_type(8))) __bf16 bf16x8;
typedef __attribute__((ext_vector_type(8))) unsigned short u16x8;
typedef __attribute__((ext_vector_type(4))) float f32x4;
typedef __attribute__((ext_vector_type(4))) unsigned int u32x4;

static __device__ __forceinline__ unsigned short f2bf(float f) {
    unsigned int u = __builtin_bit_cast(unsigned int, f);
    u += 0x7fffu + ((u >> 16) & 1u);
    return (unsigned short)(u >> 16);
}

__global__ void k_cvt_kernel(const float* __restrict__ src,
                             unsigned short* __restrict__ dst, int n4) {
    int i = blockIdx.x * blockDim.x + threadIdx.x;
    if (i >= n4) return;
    float4 v = reinterpret_cast<const float4*>(src)[i];
    ushort4 o;
    o.x = f2bf(v.x); o.y = f2bf(v.y); o.z = f2bf(v.z); o.w = f2bf(v.w);
    reinterpret_cast<ushort4*>(dst)[i] = o;
}

__global__ void v_tr_kernel(const float* __restrict__ V,
                            unsigned short* __restrict__ Vt) {
    // 64x64 tile transpose through LDS. grid (S/64, D/64, B), 256 thr.
    __shared__ unsigned short T[64][72];
    const int k0 = blockIdx.x * 64;
    const int d0 = blockIdx.y * 64;
    const int b  = blockIdx.z;
    const int t  = threadIdx.x;
    const int r  = t >> 4;
    const int c4 = (t & 15) * 4;
#pragma unroll
    for (int rep = 0; rep < 4; ++rep) {
        int ki = rep * 16 + r;
        float4 v = *reinterpret_cast<const float4*>(
            &V[((size_t)(b * S_SZ + k0 + ki)) * D_SZ + d0 + c4]);
        T[ki][c4 + 0] = f2bf(v.x); T[ki][c4 + 1] = f2bf(v.y);
        T[ki][c4 + 2] = f2bf(v.z); T[ki][c4 + 3] = f2bf(v.w);
    }
    __syncthreads();
#pragma unroll
    for (int rep = 0; rep < 4; ++rep) {
        int di = rep * 16 + r;
        ushort4 o;
        o.x = T[c4 + 0][di]; o.y = T[c4 + 1][di];
        o.z = T[c4 + 2][di]; o.w = T[c4 + 3][di];
        *reinterpret_cast<ushort4*>(
            &Vt[((size_t)(b * D_SZ + d0 + di)) * S_SZ + k0 + c4]) = o;
    }
}

__global__ __launch_bounds__(256) void mqa_fwd_kernel(
        const float* __restrict__ Q,
        const unsigned short* __restrict__ Kb,   // [B][S][D] bf16
        const unsigned short* __restrict__ Vt,   // [B][D][S] bf16
        float* __restrict__ Out)
{
    __shared__ __align__(16) unsigned short Kl[64 * 128];   // [key][d], swizzled
    __shared__ __align__(16) unsigned short Vl[128 * 64];   // [d][key], swizzled

    const int tid  = threadIdx.x;
    const int lane = tid & 63;
    const int w    = tid >> 6;
    const int l15  = lane & 15;
    const int lg   = lane >> 4;

    const int qt = blockIdx.x;
    const int h  = blockIdx.y;
    const int b  = blockIdx.z;

    // ---- Q fragments (MFMA B-operand for QK^T: col=q=l15, k=lg*8+i), log2-scaled ----
    const size_t qoff = (((size_t)b * H_SZ + h) * S_SZ + qt * QBLK + w * 16 + l15) * D_SZ;
    bf16x8 qf[4];
#pragma unroll
    for (int kc = 0; kc < 4; ++kc) {
        const float4 a = *reinterpret_cast<const float4*>(Q + qoff + kc * 32 + lg * 8);
        const float4 c = *reinterpret_cast<const float4*>(Q + qoff + kc * 32 + lg * 8 + 4);
        u16x8 u;
        u[0] = f2bf(a.x * QSCALE); u[1] = f2bf(a.y * QSCALE);
        u[2] = f2bf(a.z * QSCALE); u[3] = f2bf(a.w * QSCALE);
        u[4] = f2bf(c.x * QSCALE); u[5] = f2bf(c.y * QSCALE);
        u[6] = f2bf(c.z * QSCALE); u[7] = f2bf(c.w * QSCALE);
        qf[kc] = __builtin_bit_cast(bf16x8, u);
    }

    float m_s = -1e30f, l_s = 0.f;
    // oacc[nt][j] = O[d = nt*16 + lg*4 + j][q = l15]  (PV operand-swapped)
    f32x4 oacc[8];
#pragma unroll
    for (int n = 0; n < 8; ++n) oacc[n] = (f32x4){0.f, 0.f, 0.f, 0.f};

    const unsigned short* KbB = Kb + (size_t)b * S_SZ * D_SZ;
    const unsigned short* VtB = Vt + (size_t)b * D_SZ * S_SZ;

    // shfl source lanes for the P exchange (lane-const)
    const int s0 = l15 + ((lg & 1) << 5);  // gs = (lg&1)*2
    const int s1 = s0 + 16;                // gs = (lg&1)*2 + 1
    const bool hi = (lg & 2) != 0;         // selects n = 2kc+1 registers

    for (int t = 0; t < S_SZ / KBLK; ++t) {
        const int k0 = t * KBLK;
        __syncthreads();  // previous tile's reads done before overwrite
        // ---- stage K tile [64][128] bf16, swizzled (R1-proven) ----
#pragma unroll
        for (int j = 0; j < 4; ++j) {
            int c = tid + j * 256;
            int row = c >> 4, ch = c & 15;
            u32x4 v = *reinterpret_cast<const u32x4*>(KbB + (size_t)(k0 + row) * D_SZ + ch * 8);
            int idx = (row * 256 + ((ch * 16) ^ ((row & 7) << 4))) >> 1;
            *reinterpret_cast<u32x4*>(&Kl[idx]) = v;
        }
        // ---- stage V tile [128][64] bf16 (d-major), swizzled (R1-proven) ----
#pragma unroll
        for (int j = 0; j < 4; ++j) {
            int c = tid + j * 256;
            int dr = c >> 3, ch = c & 7;
            u32x4 v = *reinterpret_cast<const u32x4*>(VtB + (size_t)dr * S_SZ + k0 + ch * 8);
            int idx = (dr * 128 + ((ch * 16) ^ ((dr & 7) << 4))) >> 1;
            *reinterpret_cast<u32x4*>(&Vl[idx]) = v;
        }
        __syncthreads();

        // ---- swapped QK^T: lane (l15,lg) gets S[key = n*16 + lg*4 + r][q = l15] ----
        f32x4 sacc[4];
#pragma unroll
        for (int n = 0; n < 4; ++n) sacc[n] = (f32x4){0.f, 0.f, 0.f, 0.f};
#pragma unroll
        for (int kc = 0; kc < 4; ++kc) {
#pragma unroll
            for (int n = 0; n < 4; ++n) {
                int key = n * 16 + l15;
                int idx = (key * 256 + ((kc * 64 + lg * 16) ^ ((key & 7) << 4))) >> 1;
                bf16x8 kf = *reinterpret_cast<const bf16x8*>(&Kl[idx]);
                sacc[n] = __builtin_amdgcn_mfma_f32_16x16x32_bf16(kf, qf[kc], sacc[n], 0, 0, 0);
            }
        }

        // ---- online softmax, one q-row per lane, log2 domain ----
        float mx = sacc[0][0];
#pragma unroll
        for (int n = 0; n < 4; ++n) {
#pragma unroll
            for (int r = 0; r < 4; ++r) mx = fmaxf(mx, sacc[n][r]);
        }
        mx = fmaxf(mx, __shfl_xor(mx, 16));
        mx = fmaxf(mx, __shfl_xor(mx, 32));
        if (!__all(mx <= m_s + DEFER_THR)) {
            const float mnew = fmaxf(m_s, mx);
            const float corr = exp2f(m_s - mnew);  // per-q (= per-lane), no broadcast
            l_s *= corr;
            m_s = mnew;
#pragma unroll
            for (int nt = 0; nt < 8; ++nt) {
                oacc[nt][0] *= corr; oacc[nt][1] *= corr;
                oacc[nt][2] *= corr; oacc[nt][3] *= corr;
            }
        }
        float p[4][4];
        float rs = 0.f;
#pragma unroll
        for (int n = 0; n < 4; ++n) {
#pragma unroll
            for (int r = 0; r < 4; ++r) {
                p[n][r] = exp2f(sacc[n][r] - m_s);
                rs += p[n][r];
            }
        }
        rs += __shfl_xor(rs, 16);
        rs += __shfl_xor(rs, 32);
        l_s += rs;

        // ---- pack P into bf16x2 words: W[n][j] = keys (n*16+lg*4+2j, +1) ----
        unsigned int W[4][2];
#pragma unroll
        for (int n = 0; n < 4; ++n) {
#pragma unroll
            for (int j = 0; j < 2; ++j) {
                W[n][j] = (unsigned int)f2bf(p[n][2 * j])
                        | ((unsigned int)f2bf(p[n][2 * j + 1]) << 16);
            }
        }
        // ---- register exchange -> PV B-operand fragments ----
        // word(kc,m) = W[2kc + (lg>>1)][m&1] from lane l15 + 16*((lg&1)*2 + (m>>1))
        unsigned int pw0[4], pw1[4];
        {
            int a, c;
            a = __shfl((int)W[0][0], s0); c = __shfl((int)W[1][0], s0);
            pw0[0] = (unsigned int)(hi ? c : a);
            a = __shfl((int)W[0][1], s0); c = __shfl((int)W[1][1], s0);
            pw0[1] = (unsigned int)(hi ? c : a);
            a = __shfl((int)W[0][0], s1); c = __shfl((int)W[1][0], s1);
            pw0[2] = (unsigned int)(hi ? c : a);
            a = __shfl((int)W[0][1], s1); c = __shfl((int)W[1][1], s1);
            pw0[3] = (unsigned int)(hi ? c : a);
            a = __shfl((int)W[2][0], s0); c = __shfl((int)W[3][0], s0);
            pw1[0] = (unsigned int)(hi ? c : a);
            a = __shfl((int)W[2][1], s0); c = __shfl((int)W[3][1], s0);
            pw1[1] = (unsigned int)(hi ? c : a);
            a = __shfl((int)W[2][0], s1); c = __shfl((int)W[3][0], s1);
            pw1[2] = (unsigned int)(hi ? c : a);
            a = __shfl((int)W[2][1], s1); c = __shfl((int)W[3][1], s1);
            pw1[3] = (unsigned int)(hi ? c : a);
        }
        u32x4 pv0 = {pw0[0], pw0[1], pw0[2], pw0[3]};
        u32x4 pv1 = {pw1[0], pw1[1], pw1[2], pw1[3]};
        const bf16x8 pb0 = __builtin_bit_cast(bf16x8, pv0);
        const bf16x8 pb1 = __builtin_bit_cast(bf16x8, pv1);

        // ---- PV (operand-swapped): D[d][q] += V^T[d][k] * P[k][q] ----
#pragma unroll
        for (int nt = 0; nt < 8; ++nt) {
            int d = nt * 16 + l15;
            int vidx0 = (d * 128 + ((lg * 16) ^ ((d & 7) << 4))) >> 1;
            bf16x8 vf0 = *reinterpret_cast<const bf16x8*>(&Vl[vidx0]);
            oacc[nt] = __builtin_amdgcn_mfma_f32_16x16x32_bf16(vf0, pb0, oacc[nt], 0, 0, 0);
            int vidx1 = (d * 128 + ((64 + lg * 16) ^ ((d & 7) << 4))) >> 1;
            bf16x8 vf1 = *reinterpret_cast<const bf16x8*>(&Vl[vidx1]);
            oacc[nt] = __builtin_amdgcn_mfma_f32_16x16x32_bf16(vf1, pb1, oacc[nt], 0, 0, 0);
        }
    }

    // ---- epilogue: O[q=l15][d] = oacc/l, 8 x float4 stores ----
    const float linv = 1.0f / l_s;
    float* obase = Out + (((size_t)b * H_SZ + h) * S_SZ + qt * QBLK + w * 16 + l15) * D_SZ;
#pragma unroll
    for (int nt = 0; nt < 8; ++nt) {
        f32x4 o;
        o[0] = oacc[nt][0] * linv; o[1] = oacc[nt][1] * linv;
        o[2] = oacc[nt][2] * linv; o[3] = oacc[nt][3] * linv;
        *reinterpret_cast<f32x4*>(obase + nt * 16 + lg * 4) = o;
    }
}

extern "C" void kernel_launch(void* const* d_in, const int* in_sizes, int n_in,
                              void* d_out, int out_size, void* d_ws, size_t ws_size,
                              hipStream_t stream) {
    const float* Q = (const float*)d_in[0];
    const float* K = (const float*)d_in[1];
    const float* V = (const float*)d_in[2];
    float* Out = (float*)d_out;

    unsigned short* Kb = (unsigned short*)d_ws;
    unsigned short* Vt = Kb + (size_t)B_SZ * S_SZ * D_SZ;

    k_cvt_kernel<<<dim3((B_SZ * S_SZ * D_SZ / 4 + 255) / 256), dim3(256), 0, stream>>>(
        K, Kb, B_SZ * S_SZ * D_SZ / 4);
    v_tr_kernel<<<dim3(S_SZ / 64, D_SZ / 64, B_SZ), dim3(256), 0, stream>>>(V, Vt);
    mqa_fwd_kernel<<<dim3(S_SZ / QBLK, H_SZ, B_SZ), dim3(256), 0, stream>>>(Q, Kb, Vt, Out);
}

// Round 5
// 608.652 us; speedup vs baseline: 1.2531x; 1.2531x over previous
//
#include <hip/hip_runtime.h>

// MQA forward, MI355X gfx950. B=4 H=32 S=2048 D=128, fp32 I/O, bf16 MFMA.
// R5: attack LDS-read-BW ceiling (measured MfmaUtil 14-20% across R1-R4 with
// LDS bytes/FLOP 2x the reference structure). 32 q-rows/wave, QBLK=128/block,
// mfma_f32_32x32x16_bf16. Swapped QK^T: lane holds q = lane&31 -> softmax
// reduce = 1 shfl_xor(32) for max + 1 for sum. P stays in REGISTERS:
// cvt_pk_bf16 pairs + v_permlane32_swap_b32 (2x2 lane-block transpose)
// produce the PV B-fragments directly (T12). PV operand-swapped:
// oacc = mfma(V^T-frag, P-frag) -> O[d][q], lane-local rescale + 1/l.
// No P LDS, no lgkmcnt fence. LDS = Kl 16K + Vl 16K = 32KB.
// Staging / swizzle / pre-passes identical to R1/R3 (proven).

#define B_SZ 4
#define H_SZ 32
#define S_SZ 2048
#define D_SZ 128
#define QBLK 128
#define KBLK 64
// (1/sqrt(128)) * log2(e): scores live in log2 domain
#define QSCALE 0.12751743f
#define DEFER_THR 8.0f

typedef __attribute__((ext_vector_type(8))) __bf16 bf16x8;
typedef __attribute__((ext_vector_type(8))) unsigned short u16x8;
typedef __attribute__((ext_vector_type(4))) float f32x4;
typedef __attribute__((ext_vector_type(16))) float f32x16;
typedef __attribute__((ext_vector_type(4))) unsigned int u32x4;

static __device__ __forceinline__ unsigned short f2bf(float f) {
    unsigned int u = __builtin_bit_cast(unsigned int, f);
    u += 0x7fffu + ((u >> 16) & 1u);
    return (unsigned short)(u >> 16);
}

static __device__ __forceinline__ unsigned int cvtpk(float lo, float hi) {
    unsigned int r;
    asm("v_cvt_pk_bf16_f32 %0, %1, %2" : "=v"(r) : "v"(lo), "v"(hi));
    return r;
}

__global__ void k_cvt_kernel(const float* __restrict__ src,
                             unsigned short* __restrict__ dst, int n4) {
    int i = blockIdx.x * blockDim.x + threadIdx.x;
    if (i >= n4) return;
    float4 v = reinterpret_cast<const float4*>(src)[i];
    ushort4 o;
    o.x = f2bf(v.x); o.y = f2bf(v.y); o.z = f2bf(v.z); o.w = f2bf(v.w);
    reinterpret_cast<ushort4*>(dst)[i] = o;
}

__global__ void v_tr_kernel(const float* __restrict__ V,
                            unsigned short* __restrict__ Vt) {
    // 64x64 tile transpose through LDS. grid (S/64, D/64, B), 256 thr.
    __shared__ unsigned short T[64][72];
    const int k0 = blockIdx.x * 64;
    const int d0 = blockIdx.y * 64;
    const int b  = blockIdx.z;
    const int t  = threadIdx.x;
    const int r  = t >> 4;
    const int c4 = (t & 15) * 4;
#pragma unroll
    for (int rep = 0; rep < 4; ++rep) {
        int ki = rep * 16 + r;
        float4 v = *reinterpret_cast<const float4*>(
            &V[((size_t)(b * S_SZ + k0 + ki)) * D_SZ + d0 + c4]);
        T[ki][c4 + 0] = f2bf(v.x); T[ki][c4 + 1] = f2bf(v.y);
        T[ki][c4 + 2] = f2bf(v.z); T[ki][c4 + 3] = f2bf(v.w);
    }
    __syncthreads();
#pragma unroll
    for (int rep = 0; rep < 4; ++rep) {
        int di = rep * 16 + r;
        ushort4 o;
        o.x = T[c4 + 0][di]; o.y = T[c4 + 1][di];
        o.z = T[c4 + 2][di]; o.w = T[c4 + 3][di];
        *reinterpret_cast<ushort4*>(
            &Vt[((size_t)(b * D_SZ + d0 + di)) * S_SZ + k0 + c4]) = o;
    }
}

__global__ __launch_bounds__(256) void mqa_fwd_kernel(
        const float* __restrict__ Q,
        const unsigned short* __restrict__ Kb,   // [B][S][D] bf16
        const unsigned short* __restrict__ Vt,   // [B][D][S] bf16
        float* __restrict__ Out)
{
    __shared__ __align__(16) unsigned short Kl[64 * 128];   // [key][d], swizzled
    __shared__ __align__(16) unsigned short Vl[128 * 64];   // [d][key], swizzled

    const int tid  = threadIdx.x;
    const int lane = tid & 63;
    const int w    = tid >> 6;
    const int l31  = lane & 31;   // q within wave; also A-frag row
    const int hi   = lane >> 5;   // k-half selector

    const int qt = blockIdx.x;
    const int h  = blockIdx.y;
    const int b  = blockIdx.z;

    // ---- Q fragments (B-operand of 32x32x16: col=q=l31, k=hi*8+i per 16-d chunk) ----
    const size_t qoff = (((size_t)b * H_SZ + h) * S_SZ + qt * QBLK + w * 32 + l31) * D_SZ;
    bf16x8 qf[8];
#pragma unroll
    for (int kc = 0; kc < 8; ++kc) {
        const float4 a = *reinterpret_cast<const float4*>(Q + qoff + kc * 16 + hi * 8);
        const float4 c = *reinterpret_cast<const float4*>(Q + qoff + kc * 16 + hi * 8 + 4);
        u16x8 u;
        u[0] = f2bf(a.x * QSCALE); u[1] = f2bf(a.y * QSCALE);
        u[2] = f2bf(a.z * QSCALE); u[3] = f2bf(a.w * QSCALE);
        u[4] = f2bf(c.x * QSCALE); u[5] = f2bf(c.y * QSCALE);
        u[6] = f2bf(c.z * QSCALE); u[7] = f2bf(c.w * QSCALE);
        qf[kc] = __builtin_bit_cast(bf16x8, u);
    }

    float m_s = -1e30f, l_s = 0.f;
    // oacc[db]: D[d = db*32 + (r&3)+8*(r>>2)+4*hi][q = l31]
    f32x16 oacc[4];
#pragma unroll
    for (int n = 0; n < 4; ++n) {
#pragma unroll
        for (int r = 0; r < 16; ++r) oacc[n][r] = 0.f;
    }

    const unsigned short* KbB = Kb + (size_t)b * S_SZ * D_SZ;
    const unsigned short* VtB = Vt + (size_t)b * D_SZ * S_SZ;
    const char* Klc = (const char*)Kl;
    const char* Vlc = (const char*)Vl;
    const int swz = (l31 & 7) << 4;

    for (int t = 0; t < S_SZ / KBLK; ++t) {
        const int k0 = t * KBLK;
        __syncthreads();  // previous tile's reads done before overwrite
        // ---- stage K tile [64][128] bf16, swizzled (R1-proven) ----
#pragma unroll
        for (int j = 0; j < 4; ++j) {
            int c = tid + j * 256;
            int row = c >> 4, ch = c & 15;
            u32x4 v = *reinterpret_cast<const u32x4*>(KbB + (size_t)(k0 + row) * D_SZ + ch * 8);
            int idx = (row * 256 + ((ch * 16) ^ ((row & 7) << 4))) >> 1;
            *reinterpret_cast<u32x4*>(&Kl[idx]) = v;
        }
        // ---- stage V tile [128][64] bf16 (d-major), swizzled (R1-proven) ----
#pragma unroll
        for (int j = 0; j < 4; ++j) {
            int c = tid + j * 256;
            int dr = c >> 3, ch = c & 7;
            u32x4 v = *reinterpret_cast<const u32x4*>(VtB + (size_t)dr * S_SZ + k0 + ch * 8);
            int idx = (dr * 128 + ((ch * 16) ^ ((dr & 7) << 4))) >> 1;
            *reinterpret_cast<u32x4*>(&Vl[idx]) = v;
        }
        __syncthreads();

        // ---- swapped QK^T: S^T[64k][32q]; lane holds q=l31,
        //      keys kb*32 + (r&3)+8*(r>>2)+4*hi ----
        f32x16 sacc[2];
#pragma unroll
        for (int kb = 0; kb < 2; ++kb) {
#pragma unroll
            for (int r = 0; r < 16; ++r) sacc[kb][r] = 0.f;
        }
#pragma unroll
        for (int kc = 0; kc < 8; ++kc) {
#pragma unroll
            for (int kb = 0; kb < 2; ++kb) {
                // A-frag: K[key = kb*32 + l31][kc*16 + hi*8 + i]
                int off = (kb * 32 + l31) * 256 + ((kc * 32 + hi * 16) ^ swz);
                bf16x8 kf = *reinterpret_cast<const bf16x8*>(Klc + off);
                sacc[kb] = __builtin_amdgcn_mfma_f32_32x32x16_bf16(kf, qf[kc], sacc[kb], 0, 0, 0);
            }
        }

        // ---- online softmax, one q-row per lane (lane^32 holds same q), log2 ----
        float mx = sacc[0][0];
#pragma unroll
        for (int kb = 0; kb < 2; ++kb) {
#pragma unroll
            for (int r = 0; r < 16; ++r) mx = fmaxf(mx, sacc[kb][r]);
        }
        mx = fmaxf(mx, __shfl_xor(mx, 32));
        if (!__all(mx <= m_s + DEFER_THR)) {
            const float mnew = fmaxf(m_s, mx);
            const float corr = exp2f(m_s - mnew);  // lane-local (q = l31)
            l_s *= corr;
            m_s = mnew;
#pragma unroll
            for (int n = 0; n < 4; ++n) {
#pragma unroll
                for (int r = 0; r < 16; ++r) oacc[n][r] *= corr;
            }
        }
        float rs = 0.f;
        bf16x8 PB[4];  // PV B-frags: PB[kb*2+c], elem i = P[kb*32+c*16+hi*8+i][q]
#pragma unroll
        for (int kb = 0; kb < 2; ++kb) {
            float p[16];
#pragma unroll
            for (int r = 0; r < 16; ++r) {
                p[r] = exp2f(sacc[kb][r] - m_s);
                rs += p[r];
            }
            // pack pairs: a_j = keys 4hi + {...} (C-reg order)
            unsigned int a0 = cvtpk(p[0],  p[1]);   // 4hi + {0,1}
            unsigned int a1 = cvtpk(p[2],  p[3]);   // 4hi + {2,3}
            unsigned int a2 = cvtpk(p[4],  p[5]);   // 4hi + {8,9}
            unsigned int a3 = cvtpk(p[6],  p[7]);   // 4hi + {10,11}
            unsigned int a4 = cvtpk(p[8],  p[9]);   // 4hi + {16,17}
            unsigned int a5 = cvtpk(p[10], p[11]);  // 4hi + {18,19}
            unsigned int a6 = cvtpk(p[12], p[13]);  // 4hi + {24,25}
            unsigned int a7 = cvtpk(p[14], p[15]);  // 4hi + {26,27}
            // 2x2 lane-block transpose across lane 32 boundary:
            // after swap(x,y): x = [x_lo, y_lo], y = [x_hi, y_hi]
            asm("v_permlane32_swap_b32 %0, %1" : "+v"(a0), "+v"(a2));
            asm("v_permlane32_swap_b32 %0, %1" : "+v"(a1), "+v"(a3));
            asm("v_permlane32_swap_b32 %0, %1" : "+v"(a4), "+v"(a6));
            asm("v_permlane32_swap_b32 %0, %1" : "+v"(a5), "+v"(a7));
            // now: a0 = 8hi+{0,1}, a1 = 8hi+{2,3}, a2 = 8hi+{4,5}, a3 = 8hi+{6,7}
            //      a4..a7 same +16 (chunk c=1)
            u32x4 c0 = {a0, a1, a2, a3};
            u32x4 c1 = {a4, a5, a6, a7};
            PB[kb * 2 + 0] = __builtin_bit_cast(bf16x8, c0);
            PB[kb * 2 + 1] = __builtin_bit_cast(bf16x8, c1);
        }
        rs += __shfl_xor(rs, 32);
        l_s += rs;

        // ---- PV (operand-swapped): D[d][q] += V^T[d][k] * P[k][q] ----
#pragma unroll
        for (int kch = 0; kch < 4; ++kch) {
#pragma unroll
            for (int db = 0; db < 4; ++db) {
                // A-frag: V^T[d = db*32 + l31][kch*16 + hi*8 + i]
                int off = (db * 32 + l31) * 128 + ((kch * 32 + hi * 16) ^ swz);
                bf16x8 vf = *reinterpret_cast<const bf16x8*>(Vlc + off);
                oacc[db] = __builtin_amdgcn_mfma_f32_32x32x16_bf16(vf, PB[kch], oacc[db], 0, 0, 0);
            }
        }
    }

    // ---- epilogue: O[q = l31][d] = oacc/l, 16 x float4 stores ----
    const float linv = 1.0f / l_s;
    float* obase = Out + (((size_t)b * H_SZ + h) * S_SZ + qt * QBLK + w * 32 + l31) * D_SZ;
#pragma unroll
    for (int db = 0; db < 4; ++db) {
#pragma unroll
        for (int rr = 0; rr < 4; ++rr) {
            f32x4 o;
            o[0] = oacc[db][rr * 4 + 0] * linv;
            o[1] = oacc[db][rr * 4 + 1] * linv;
            o[2] = oacc[db][rr * 4 + 2] * linv;
            o[3] = oacc[db][rr * 4 + 3] * linv;
            *reinterpret_cast<f32x4*>(obase + db * 32 + rr * 8 + hi * 4) = o;
        }
    }
}

extern "C" void kernel_launch(void* const* d_in, const int* in_sizes, int n_in,
                              void* d_out, int out_size, void* d_ws, size_t ws_size,
                              hipStream_t stream) {
    const float* Q = (const float*)d_in[0];
    const float* K = (const float*)d_in[1];
    const float* V = (const float*)d_in[2];
    float* Out = (float*)d_out;

    unsigned short* Kb = (unsigned short*)d_ws;
    unsigned short* Vt = Kb + (size_t)B_SZ * S_SZ * D_SZ;

    k_cvt_kernel<<<dim3((B_SZ * S_SZ * D_SZ / 4 + 255) / 256), dim3(256), 0, stream>>>(
        K, Kb, B_SZ * S_SZ * D_SZ / 4);
    v_tr_kernel<<<dim3(S_SZ / 64, D_SZ / 64, B_SZ), dim3(256), 0, stream>>>(V, Vt);
    mqa_fwd_kernel<<<dim3(S_SZ / QBLK, H_SZ, B_SZ), dim3(256), 0, stream>>>(Q, Kb, Vt, Out);
}

// Round 6
// 378.732 us; speedup vs baseline: 2.0138x; 1.6071x over previous
//
#include <hip/hip_runtime.h>

// MQA forward, MI355X gfx950. B=4 H=32 S=2048 D=128, fp32 I/O, bf16 MFMA.
// R6 = R5 minus the register spill (R5: WRITE_SIZE 329MB = ~196MB scratch,
// VGPR cap 136 < ~175 live, occupancy 11.7%).
//   1) __launch_bounds__(256, 2): VGPR budget 256.
//   2) exp2 in place into sacc (kills float p[16]).
//   3) PV MFMAs moved inside the kb loop (PB lifetime = half tile).
// Structure unchanged from R5: 32 q-rows/wave, QBLK=128, 32x32x16 MFMA,
// swapped QK^T, in-register softmax (1 shfl max + 1 shfl sum), T12
// cvt_pk + permlane32_swap P-path, operand-swapped PV, O[d][q] lane-local.

#define B_SZ 4
#define H_SZ 32
#define S_SZ 2048
#define D_SZ 128
#define QBLK 128
#define KBLK 64
// (1/sqrt(128)) * log2(e): scores live in log2 domain
#define QSCALE 0.12751743f
#define DEFER_THR 8.0f

typedef __attribute__((ext_vector_type(8))) __bf16 bf16x8;
typedef __attribute__((ext_vector_type(8))) unsigned short u16x8;
typedef __attribute__((ext_vector_type(4))) float f32x4;
typedef __attribute__((ext_vector_type(16))) float f32x16;
typedef __attribute__((ext_vector_type(4))) unsigned int u32x4;

static __device__ __forceinline__ unsigned short f2bf(float f) {
    unsigned int u = __builtin_bit_cast(unsigned int, f);
    u += 0x7fffu + ((u >> 16) & 1u);
    return (unsigned short)(u >> 16);
}

static __device__ __forceinline__ unsigned int cvtpk(float lo, float hi) {
    unsigned int r;
    asm("v_cvt_pk_bf16_f32 %0, %1, %2" : "=v"(r) : "v"(lo), "v"(hi));
    return r;
}

__global__ void k_cvt_kernel(const float* __restrict__ src,
                             unsigned short* __restrict__ dst, int n4) {
    int i = blockIdx.x * blockDim.x + threadIdx.x;
    if (i >= n4) return;
    float4 v = reinterpret_cast<const float4*>(src)[i];
    ushort4 o;
    o.x = f2bf(v.x); o.y = f2bf(v.y); o.z = f2bf(v.z); o.w = f2bf(v.w);
    reinterpret_cast<ushort4*>(dst)[i] = o;
}

__global__ void v_tr_kernel(const float* __restrict__ V,
                            unsigned short* __restrict__ Vt) {
    // 64x64 tile transpose through LDS. grid (S/64, D/64, B), 256 thr.
    __shared__ unsigned short T[64][72];
    const int k0 = blockIdx.x * 64;
    const int d0 = blockIdx.y * 64;
    const int b  = blockIdx.z;
    const int t  = threadIdx.x;
    const int r  = t >> 4;
    const int c4 = (t & 15) * 4;
#pragma unroll
    for (int rep = 0; rep < 4; ++rep) {
        int ki = rep * 16 + r;
        float4 v = *reinterpret_cast<const float4*>(
            &V[((size_t)(b * S_SZ + k0 + ki)) * D_SZ + d0 + c4]);
        T[ki][c4 + 0] = f2bf(v.x); T[ki][c4 + 1] = f2bf(v.y);
        T[ki][c4 + 2] = f2bf(v.z); T[ki][c4 + 3] = f2bf(v.w);
    }
    __syncthreads();
#pragma unroll
    for (int rep = 0; rep < 4; ++rep) {
        int di = rep * 16 + r;
        ushort4 o;
        o.x = T[c4 + 0][di]; o.y = T[c4 + 1][di];
        o.z = T[c4 + 2][di]; o.w = T[c4 + 3][di];
        *reinterpret_cast<ushort4*>(
            &Vt[((size_t)(b * D_SZ + d0 + di)) * S_SZ + k0 + c4]) = o;
    }
}

__global__ __launch_bounds__(256, 2) void mqa_fwd_kernel(
        const float* __restrict__ Q,
        const unsigned short* __restrict__ Kb,   // [B][S][D] bf16
        const unsigned short* __restrict__ Vt,   // [B][D][S] bf16
        float* __restrict__ Out)
{
    __shared__ __align__(16) unsigned short Kl[64 * 128];   // [key][d], swizzled
    __shared__ __align__(16) unsigned short Vl[128 * 64];   // [d][key], swizzled

    const int tid  = threadIdx.x;
    const int lane = tid & 63;
    const int w    = tid >> 6;
    const int l31  = lane & 31;   // q within wave; also A-frag row
    const int hi   = lane >> 5;   // k-half selector

    const int qt = blockIdx.x;
    const int h  = blockIdx.y;
    const int b  = blockIdx.z;

    // ---- Q fragments (B-operand of 32x32x16: col=q=l31, k=hi*8+i per 16-d chunk) ----
    const size_t qoff = (((size_t)b * H_SZ + h) * S_SZ + qt * QBLK + w * 32 + l31) * D_SZ;
    bf16x8 qf[8];
#pragma unroll
    for (int kc = 0; kc < 8; ++kc) {
        const float4 a = *reinterpret_cast<const float4*>(Q + qoff + kc * 16 + hi * 8);
        const float4 c = *reinterpret_cast<const float4*>(Q + qoff + kc * 16 + hi * 8 + 4);
        u16x8 u;
        u[0] = f2bf(a.x * QSCALE); u[1] = f2bf(a.y * QSCALE);
        u[2] = f2bf(a.z * QSCALE); u[3] = f2bf(a.w * QSCALE);
        u[4] = f2bf(c.x * QSCALE); u[5] = f2bf(c.y * QSCALE);
        u[6] = f2bf(c.z * QSCALE); u[7] = f2bf(c.w * QSCALE);
        qf[kc] = __builtin_bit_cast(bf16x8, u);
    }

    float m_s = -1e30f, l_s = 0.f;
    // oacc[db]: D[d = db*32 + (r&3)+8*(r>>2)+4*hi][q = l31]
    f32x16 oacc[4];
#pragma unroll
    for (int n = 0; n < 4; ++n) {
#pragma unroll
        for (int r = 0; r < 16; ++r) oacc[n][r] = 0.f;
    }

    const unsigned short* KbB = Kb + (size_t)b * S_SZ * D_SZ;
    const unsigned short* VtB = Vt + (size_t)b * D_SZ * S_SZ;
    const char* Klc = (const char*)Kl;
    const char* Vlc = (const char*)Vl;
    const int swz = (l31 & 7) << 4;

    for (int t = 0; t < S_SZ / KBLK; ++t) {
        const int k0 = t * KBLK;
        __syncthreads();  // previous tile's reads done before overwrite
        // ---- stage K tile [64][128] bf16, swizzled (R1-proven) ----
#pragma unroll
        for (int j = 0; j < 4; ++j) {
            int c = tid + j * 256;
            int row = c >> 4, ch = c & 15;
            u32x4 v = *reinterpret_cast<const u32x4*>(KbB + (size_t)(k0 + row) * D_SZ + ch * 8);
            int idx = (row * 256 + ((ch * 16) ^ ((row & 7) << 4))) >> 1;
            *reinterpret_cast<u32x4*>(&Kl[idx]) = v;
        }
        // ---- stage V tile [128][64] bf16 (d-major), swizzled (R1-proven) ----
#pragma unroll
        for (int j = 0; j < 4; ++j) {
            int c = tid + j * 256;
            int dr = c >> 3, ch = c & 7;
            u32x4 v = *reinterpret_cast<const u32x4*>(VtB + (size_t)dr * S_SZ + k0 + ch * 8);
            int idx = (dr * 128 + ((ch * 16) ^ ((dr & 7) << 4))) >> 1;
            *reinterpret_cast<u32x4*>(&Vl[idx]) = v;
        }
        __syncthreads();

        // ---- swapped QK^T: S^T[64k][32q]; lane holds q=l31,
        //      keys kb*32 + (r&3)+8*(r>>2)+4*hi ----
        f32x16 sacc[2];
#pragma unroll
        for (int kb = 0; kb < 2; ++kb) {
#pragma unroll
            for (int r = 0; r < 16; ++r) sacc[kb][r] = 0.f;
        }
#pragma unroll
        for (int kc = 0; kc < 8; ++kc) {
#pragma unroll
            for (int kb = 0; kb < 2; ++kb) {
                // A-frag: K[key = kb*32 + l31][kc*16 + hi*8 + i]
                int off = (kb * 32 + l31) * 256 + ((kc * 32 + hi * 16) ^ swz);
                bf16x8 kf = *reinterpret_cast<const bf16x8*>(Klc + off);
                sacc[kb] = __builtin_amdgcn_mfma_f32_32x32x16_bf16(kf, qf[kc], sacc[kb], 0, 0, 0);
            }
        }

        // ---- online softmax, one q-row per lane (lane^32 holds same q), log2 ----
        float mx = sacc[0][0];
#pragma unroll
        for (int kb = 0; kb < 2; ++kb) {
#pragma unroll
            for (int r = 0; r < 16; ++r) mx = fmaxf(mx, sacc[kb][r]);
        }
        mx = fmaxf(mx, __shfl_xor(mx, 32));
        if (!__all(mx <= m_s + DEFER_THR)) {
            const float mnew = fmaxf(m_s, mx);
            const float corr = exp2f(m_s - mnew);  // lane-local (q = l31)
            l_s *= corr;
            m_s = mnew;
#pragma unroll
            for (int n = 0; n < 4; ++n) {
#pragma unroll
                for (int r = 0; r < 16; ++r) oacc[n][r] *= corr;
            }
        }

        float rs = 0.f;
#pragma unroll
        for (int kb = 0; kb < 2; ++kb) {
            // exp2 IN PLACE into sacc[kb] (no p[] staging array)
#pragma unroll
            for (int r = 0; r < 16; ++r) {
                sacc[kb][r] = exp2f(sacc[kb][r] - m_s);
                rs += sacc[kb][r];
            }
            // pack pairs (C-reg order), then 2x2 lane-block transpose
            unsigned int a0 = cvtpk(sacc[kb][0],  sacc[kb][1]);
            unsigned int a1 = cvtpk(sacc[kb][2],  sacc[kb][3]);
            unsigned int a2 = cvtpk(sacc[kb][4],  sacc[kb][5]);
            unsigned int a3 = cvtpk(sacc[kb][6],  sacc[kb][7]);
            unsigned int a4 = cvtpk(sacc[kb][8],  sacc[kb][9]);
            unsigned int a5 = cvtpk(sacc[kb][10], sacc[kb][11]);
            unsigned int a6 = cvtpk(sacc[kb][12], sacc[kb][13]);
            unsigned int a7 = cvtpk(sacc[kb][14], sacc[kb][15]);
            asm("v_permlane32_swap_b32 %0, %1" : "+v"(a0), "+v"(a2));
            asm("v_permlane32_swap_b32 %0, %1" : "+v"(a1), "+v"(a3));
            asm("v_permlane32_swap_b32 %0, %1" : "+v"(a4), "+v"(a6));
            asm("v_permlane32_swap_b32 %0, %1" : "+v"(a5), "+v"(a7));
            // a0..a3 = chunk c=0 (keys kb*32 + hi*8 + 0..7, q=l31)
            // a4..a7 = chunk c=1 (keys kb*32 + 16 + hi*8 + 0..7)
            u32x4 c0 = {a0, a1, a2, a3};
            u32x4 c1 = {a4, a5, a6, a7};
            const bf16x8 PB0 = __builtin_bit_cast(bf16x8, c0);
            const bf16x8 PB1 = __builtin_bit_cast(bf16x8, c1);

            // ---- PV for this kb (operand-swapped): D[d][q] += V^T[d][k]*P[k][q] ----
#pragma unroll
            for (int db = 0; db < 4; ++db) {
                int off0 = (db * 32 + l31) * 128 + (((kb * 2 + 0) * 32 + hi * 16) ^ swz);
                bf16x8 vf0 = *reinterpret_cast<const bf16x8*>(Vlc + off0);
                oacc[db] = __builtin_amdgcn_mfma_f32_32x32x16_bf16(vf0, PB0, oacc[db], 0, 0, 0);
                int off1 = (db * 32 + l31) * 128 + (((kb * 2 + 1) * 32 + hi * 16) ^ swz);
                bf16x8 vf1 = *reinterpret_cast<const bf16x8*>(Vlc + off1);
                oacc[db] = __builtin_amdgcn_mfma_f32_32x32x16_bf16(vf1, PB1, oacc[db], 0, 0, 0);
            }
        }
        rs += __shfl_xor(rs, 32);
        l_s += rs;
    }

    // ---- epilogue: O[q = l31][d] = oacc/l, 16 x float4 stores ----
    const float linv = 1.0f / l_s;
    float* obase = Out + (((size_t)b * H_SZ + h) * S_SZ + qt * QBLK + w * 32 + l31) * D_SZ;
#pragma unroll
    for (int db = 0; db < 4; ++db) {
#pragma unroll
        for (int rr = 0; rr < 4; ++rr) {
            f32x4 o;
            o[0] = oacc[db][rr * 4 + 0] * linv;
            o[1] = oacc[db][rr * 4 + 1] * linv;
            o[2] = oacc[db][rr * 4 + 2] * linv;
            o[3] = oacc[db][rr * 4 + 3] * linv;
            *reinterpret_cast<f32x4*>(obase + db * 32 + rr * 8 + hi * 4) = o;
        }
    }
}

extern "C" void kernel_launch(void* const* d_in, const int* in_sizes, int n_in,
                              void* d_out, int out_size, void* d_ws, size_t ws_size,
                              hipStream_t stream) {
    const float* Q = (const float*)d_in[0];
    const float* K = (const float*)d_in[1];
    const float* V = (const float*)d_in[2];
    float* Out = (float*)d_out;

    unsigned short* Kb = (unsigned short*)d_ws;
    unsigned short* Vt = Kb + (size_t)B_SZ * S_SZ * D_SZ;

    k_cvt_kernel<<<dim3((B_SZ * S_SZ * D_SZ / 4 + 255) / 256), dim3(256), 0, stream>>>(
        K, Kb, B_SZ * S_SZ * D_SZ / 4);
    v_tr_kernel<<<dim3(S_SZ / 64, D_SZ / 64, B_SZ), dim3(256), 0, stream>>>(V, Vt);
    mqa_fwd_kernel<<<dim3(S_SZ / QBLK, H_SZ, B_SZ), dim3(256), 0, stream>>>(Q, Kb, Vt, Out);
}

// Round 7
// 354.575 us; speedup vs baseline: 2.1510x; 1.0681x over previous
//
#include <hip/hip_runtime.h>

// MQA forward, MI355X gfx950. B=4 H=32 S=2048 D=128, fp32 I/O, bf16 MFMA.
// R7 = R6 + T14 async-stage split + LDS double-buffer, single barrier/tile:
//   iter t: barrier -> issue 8 global_load_dwordx4 (tile t+1 -> regs)
//           -> compute tile t from buf[cur] (loads hide under 32 MFMAs)
//           -> ds_write regs -> buf[cur^1].
// Prefetch never crosses a barrier, so __syncthreads' vmcnt(0) drain is free.
// Compute/softmax/P-path byte-identical to R6 (proven):
// 32 q-rows/wave, QBLK=128, 32x32x16 MFMA, swapped QK^T, in-register softmax,
// cvt_pk + permlane32_swap P-fragments, operand-swapped PV, O[d][q] lane-local.

#define B_SZ 4
#define H_SZ 32
#define S_SZ 2048
#define D_SZ 128
#define QBLK 128
#define KBLK 64
#define NT (S_SZ / KBLK)
// (1/sqrt(128)) * log2(e): scores live in log2 domain
#define QSCALE 0.12751743f
#define DEFER_THR 8.0f

typedef __attribute__((ext_vector_type(8))) __bf16 bf16x8;
typedef __attribute__((ext_vector_type(8))) unsigned short u16x8;
typedef __attribute__((ext_vector_type(4))) float f32x4;
typedef __attribute__((ext_vector_type(16))) float f32x16;
typedef __attribute__((ext_vector_type(4))) unsigned int u32x4;

static __device__ __forceinline__ unsigned short f2bf(float f) {
    unsigned int u = __builtin_bit_cast(unsigned int, f);
    u += 0x7fffu + ((u >> 16) & 1u);
    return (unsigned short)(u >> 16);
}

static __device__ __forceinline__ unsigned int cvtpk(float lo, float hi) {
    unsigned int r;
    asm("v_cvt_pk_bf16_f32 %0, %1, %2" : "=v"(r) : "v"(lo), "v"(hi));
    return r;
}

__global__ void k_cvt_kernel(const float* __restrict__ src,
                             unsigned short* __restrict__ dst, int n4) {
    int i = blockIdx.x * blockDim.x + threadIdx.x;
    if (i >= n4) return;
    float4 v = reinterpret_cast<const float4*>(src)[i];
    ushort4 o;
    o.x = f2bf(v.x); o.y = f2bf(v.y); o.z = f2bf(v.z); o.w = f2bf(v.w);
    reinterpret_cast<ushort4*>(dst)[i] = o;
}

__global__ void v_tr_kernel(const float* __restrict__ V,
                            unsigned short* __restrict__ Vt) {
    // 64x64 tile transpose through LDS. grid (S/64, D/64, B), 256 thr.
    __shared__ unsigned short T[64][72];
    const int k0 = blockIdx.x * 64;
    const int d0 = blockIdx.y * 64;
    const int b  = blockIdx.z;
    const int t  = threadIdx.x;
    const int r  = t >> 4;
    const int c4 = (t & 15) * 4;
#pragma unroll
    for (int rep = 0; rep < 4; ++rep) {
        int ki = rep * 16 + r;
        float4 v = *reinterpret_cast<const float4*>(
            &V[((size_t)(b * S_SZ + k0 + ki)) * D_SZ + d0 + c4]);
        T[ki][c4 + 0] = f2bf(v.x); T[ki][c4 + 1] = f2bf(v.y);
        T[ki][c4 + 2] = f2bf(v.z); T[ki][c4 + 3] = f2bf(v.w);
    }
    __syncthreads();
#pragma unroll
    for (int rep = 0; rep < 4; ++rep) {
        int di = rep * 16 + r;
        ushort4 o;
        o.x = T[c4 + 0][di]; o.y = T[c4 + 1][di];
        o.z = T[c4 + 2][di]; o.w = T[c4 + 3][di];
        *reinterpret_cast<ushort4*>(
            &Vt[((size_t)(b * D_SZ + d0 + di)) * S_SZ + k0 + c4]) = o;
    }
}

__global__ __launch_bounds__(256, 2) void mqa_fwd_kernel(
        const float* __restrict__ Q,
        const unsigned short* __restrict__ Kb,   // [B][S][D] bf16
        const unsigned short* __restrict__ Vt,   // [B][D][S] bf16
        float* __restrict__ Out)
{
    __shared__ __align__(16) unsigned short Kl[2][64 * 128];   // [key][d], swizzled
    __shared__ __align__(16) unsigned short Vl[2][128 * 64];   // [d][key], swizzled

    const int tid  = threadIdx.x;
    const int lane = tid & 63;
    const int w    = tid >> 6;
    const int l31  = lane & 31;   // q within wave; also A-frag row
    const int hi   = lane >> 5;   // k-half selector

    const int qt = blockIdx.x;
    const int h  = blockIdx.y;
    const int b  = blockIdx.z;

    // ---- staging lane constants (same mapping as R6's proven staging) ----
    const int krow = tid >> 4, kch = tid & 15;     // K: 16 rows x 16 chunks / j
    const int vdr  = tid >> 3, vch = tid & 7;      // V: 32 rows x 8 chunks / j
    int ksrc[4], kidx[4], vsrc[4], vidx[4];        // src: shorts; idx: bytes
#pragma unroll
    for (int j = 0; j < 4; ++j) {
        const int kr = krow + j * 16;
        ksrc[j] = kr * D_SZ + kch * 8;
        kidx[j] = kr * 256 + ((kch * 16) ^ ((kr & 7) << 4));
        const int dr = vdr + j * 32;
        vsrc[j] = dr * S_SZ + vch * 8;
        vidx[j] = dr * 128 + ((vch * 16) ^ ((dr & 7) << 4));
    }

    // ---- Q fragments (B-operand of 32x32x16: col=q=l31, k=hi*8+i per 16-d chunk) ----
    const size_t qoff = (((size_t)b * H_SZ + h) * S_SZ + qt * QBLK + w * 32 + l31) * D_SZ;
    bf16x8 qf[8];
#pragma unroll
    for (int kc = 0; kc < 8; ++kc) {
        const float4 a = *reinterpret_cast<const float4*>(Q + qoff + kc * 16 + hi * 8);
        const float4 c = *reinterpret_cast<const float4*>(Q + qoff + kc * 16 + hi * 8 + 4);
        u16x8 u;
        u[0] = f2bf(a.x * QSCALE); u[1] = f2bf(a.y * QSCALE);
        u[2] = f2bf(a.z * QSCALE); u[3] = f2bf(a.w * QSCALE);
        u[4] = f2bf(c.x * QSCALE); u[5] = f2bf(c.y * QSCALE);
        u[6] = f2bf(c.z * QSCALE); u[7] = f2bf(c.w * QSCALE);
        qf[kc] = __builtin_bit_cast(bf16x8, u);
    }

    float m_s = -1e30f, l_s = 0.f;
    // oacc[db]: D[d = db*32 + (r&3)+8*(r>>2)+4*hi][q = l31]
    f32x16 oacc[4];
#pragma unroll
    for (int n = 0; n < 4; ++n) {
#pragma unroll
        for (int r = 0; r < 16; ++r) oacc[n][r] = 0.f;
    }

    const unsigned short* KbB = Kb + (size_t)b * S_SZ * D_SZ;
    const unsigned short* VtB = Vt + (size_t)b * D_SZ * S_SZ;
    const int swz = (l31 & 7) << 4;

    // ---- prologue: stage tile 0 into buffer 0 ----
    {
        u32x4 kr0[4], vr0[4];
#pragma unroll
        for (int j = 0; j < 4; ++j)
            kr0[j] = *reinterpret_cast<const u32x4*>(KbB + ksrc[j]);
#pragma unroll
        for (int j = 0; j < 4; ++j)
            vr0[j] = *reinterpret_cast<const u32x4*>(VtB + vsrc[j]);
#pragma unroll
        for (int j = 0; j < 4; ++j)
            *reinterpret_cast<u32x4*>((char*)Kl[0] + kidx[j]) = kr0[j];
#pragma unroll
        for (int j = 0; j < 4; ++j)
            *reinterpret_cast<u32x4*>((char*)Vl[0] + vidx[j]) = vr0[j];
    }

    int cur = 0;
    for (int t = 0; t < NT; ++t) {
        __syncthreads();  // buf[cur] staged by all waves; buf[cur^1] reads done

        // ---- T14: issue tile t+1 global loads now; land them after compute ----
        u32x4 kpre[4], vpre[4];
        const bool pf = (t + 1 < NT);
        if (pf) {
            const int k0n = (t + 1) * KBLK;
#pragma unroll
            for (int j = 0; j < 4; ++j)
                kpre[j] = *reinterpret_cast<const u32x4*>(KbB + k0n * D_SZ + ksrc[j]);
#pragma unroll
            for (int j = 0; j < 4; ++j)
                vpre[j] = *reinterpret_cast<const u32x4*>(VtB + k0n + vsrc[j]);
        }

        const char* Klc = (const char*)Kl[cur];
        const char* Vlc = (const char*)Vl[cur];

        // ---- swapped QK^T: lane holds q=l31, keys kb*32 + (r&3)+8*(r>>2)+4*hi ----
        f32x16 sacc[2];
#pragma unroll
        for (int kb = 0; kb < 2; ++kb) {
#pragma unroll
            for (int r = 0; r < 16; ++r) sacc[kb][r] = 0.f;
        }
#pragma unroll
        for (int kc = 0; kc < 8; ++kc) {
#pragma unroll
            for (int kb = 0; kb < 2; ++kb) {
                int off = (kb * 32 + l31) * 256 + ((kc * 32 + hi * 16) ^ swz);
                bf16x8 kf = *reinterpret_cast<const bf16x8*>(Klc + off);
                sacc[kb] = __builtin_amdgcn_mfma_f32_32x32x16_bf16(kf, qf[kc], sacc[kb], 0, 0, 0);
            }
        }

        // ---- online softmax, one q-row per lane (lane^32 same q), log2 domain ----
        float mx = sacc[0][0];
#pragma unroll
        for (int kb = 0; kb < 2; ++kb) {
#pragma unroll
            for (int r = 0; r < 16; ++r) mx = fmaxf(mx, sacc[kb][r]);
        }
        mx = fmaxf(mx, __shfl_xor(mx, 32));
        if (!__all(mx <= m_s + DEFER_THR)) {
            const float mnew = fmaxf(m_s, mx);
            const float corr = exp2f(m_s - mnew);  // lane-local (q = l31)
            l_s *= corr;
            m_s = mnew;
#pragma unroll
            for (int n = 0; n < 4; ++n) {
#pragma unroll
                for (int r = 0; r < 16; ++r) oacc[n][r] *= corr;
            }
        }

        float rs = 0.f;
#pragma unroll
        for (int kb = 0; kb < 2; ++kb) {
            // exp2 in place into sacc[kb]
#pragma unroll
            for (int r = 0; r < 16; ++r) {
                sacc[kb][r] = exp2f(sacc[kb][r] - m_s);
                rs += sacc[kb][r];
            }
            // pack pairs (C-reg order), then 2x2 lane-block transpose
            unsigned int a0 = cvtpk(sacc[kb][0],  sacc[kb][1]);
            unsigned int a1 = cvtpk(sacc[kb][2],  sacc[kb][3]);
            unsigned int a2 = cvtpk(sacc[kb][4],  sacc[kb][5]);
            unsigned int a3 = cvtpk(sacc[kb][6],  sacc[kb][7]);
            unsigned int a4 = cvtpk(sacc[kb][8],  sacc[kb][9]);
            unsigned int a5 = cvtpk(sacc[kb][10], sacc[kb][11]);
            unsigned int a6 = cvtpk(sacc[kb][12], sacc[kb][13]);
            unsigned int a7 = cvtpk(sacc[kb][14], sacc[kb][15]);
            asm("v_permlane32_swap_b32 %0, %1" : "+v"(a0), "+v"(a2));
            asm("v_permlane32_swap_b32 %0, %1" : "+v"(a1), "+v"(a3));
            asm("v_permlane32_swap_b32 %0, %1" : "+v"(a4), "+v"(a6));
            asm("v_permlane32_swap_b32 %0, %1" : "+v"(a5), "+v"(a7));
            u32x4 c0 = {a0, a1, a2, a3};
            u32x4 c1 = {a4, a5, a6, a7};
            const bf16x8 PB0 = __builtin_bit_cast(bf16x8, c0);
            const bf16x8 PB1 = __builtin_bit_cast(bf16x8, c1);

            // ---- PV for this kb (operand-swapped): D[d][q] += V^T[d][k]*P[k][q] ----
#pragma unroll
            for (int db = 0; db < 4; ++db) {
                int off0 = (db * 32 + l31) * 128 + (((kb * 2 + 0) * 32 + hi * 16) ^ swz);
                bf16x8 vf0 = *reinterpret_cast<const bf16x8*>(Vlc + off0);
                oacc[db] = __builtin_amdgcn_mfma_f32_32x32x16_bf16(vf0, PB0, oacc[db], 0, 0, 0);
                int off1 = (db * 32 + l31) * 128 + (((kb * 2 + 1) * 32 + hi * 16) ^ swz);
                bf16x8 vf1 = *reinterpret_cast<const bf16x8*>(Vlc + off1);
                oacc[db] = __builtin_amdgcn_mfma_f32_32x32x16_bf16(vf1, PB1, oacc[db], 0, 0, 0);
            }
        }
        rs += __shfl_xor(rs, 32);
        l_s += rs;

        // ---- land the prefetch into the other buffer (visible after next barrier) ----
        if (pf) {
            char* Kn = (char*)Kl[cur ^ 1];
            char* Vn = (char*)Vl[cur ^ 1];
#pragma unroll
            for (int j = 0; j < 4; ++j)
                *reinterpret_cast<u32x4*>(Kn + kidx[j]) = kpre[j];
#pragma unroll
            for (int j = 0; j < 4; ++j)
                *reinterpret_cast<u32x4*>(Vn + vidx[j]) = vpre[j];
        }
        cur ^= 1;
    }

    // ---- epilogue: O[q = l31][d] = oacc/l, 16 x float4 stores ----
    const float linv = 1.0f / l_s;
    float* obase = Out + (((size_t)b * H_SZ + h) * S_SZ + qt * QBLK + w * 32 + l31) * D_SZ;
#pragma unroll
    for (int db = 0; db < 4; ++db) {
#pragma unroll
        for (int rr = 0; rr < 4; ++rr) {
            f32x4 o;
            o[0] = oacc[db][rr * 4 + 0] * linv;
            o[1] = oacc[db][rr * 4 + 1] * linv;
            o[2] = oacc[db][rr * 4 + 2] * linv;
            o[3] = oacc[db][rr * 4 + 3] * linv;
            *reinterpret_cast<f32x4*>(obase + db * 32 + rr * 8 + hi * 4) = o;
        }
    }
}

extern "C" void kernel_launch(void* const* d_in, const int* in_sizes, int n_in,
                              void* d_out, int out_size, void* d_ws, size_t ws_size,
                              hipStream_t stream) {
    const float* Q = (const float*)d_in[0];
    const float* K = (const float*)d_in[1];
    const float* V = (const float*)d_in[2];
    float* Out = (float*)d_out;

    unsigned short* Kb = (unsigned short*)d_ws;
    unsigned short* Vt = Kb + (size_t)B_SZ * S_SZ * D_SZ;

    k_cvt_kernel<<<dim3((B_SZ * S_SZ * D_SZ / 4 + 255) / 256), dim3(256), 0, stream>>>(
        K, Kb, B_SZ * S_SZ * D_SZ / 4);
    v_tr_kernel<<<dim3(S_SZ / 64, D_SZ / 64, B_SZ), dim3(256), 0, stream>>>(V, Vt);
    mqa_fwd_kernel<<<dim3(S_SZ / QBLK, H_SZ, B_SZ), dim3(256), 0, stream>>>(Q, Kb, Vt, Out);
}

// Round 8
// 348.059 us; speedup vs baseline: 2.1912x; 1.0187x over previous
//
#include <hip/hip_runtime.h>

// MQA forward, MI355X gfx950. B=4 H=32 S=2048 D=128, fp32 I/O, bf16 MFMA.
// R8 = R7 + deferred-PV software pipeline (T15-style) + setprio (T5):
//   iter t: barrier -> prefetch-issue(t+1) -> QK^T(t) [16 MFMA]
//           -> PV(t-1) [16 MFMA, independent of softmax(t) -> overlaps it]
//           -> softmax(t) -> PB regs -> ds_write prefetch.
// V triple-buffered (PV(t-1) reads V(t-1) while staging writes V(t+1));
// K double-buffered. LDS = 32K + 48K = 80KB (2 blocks/CU exactly).
// Math/fragments byte-identical to R6/R7 (proven): 32 q-rows/wave, QBLK=128,
// 32x32x16 MFMA, swapped QK^T, in-register softmax, cvt_pk+permlane32_swap
// P-path, operand-swapped PV, O[d][q] lane-local.

#define B_SZ 4
#define H_SZ 32
#define S_SZ 2048
#define D_SZ 128
#define QBLK 128
#define KBLK 64
#define NT (S_SZ / KBLK)
// (1/sqrt(128)) * log2(e): scores live in log2 domain
#define QSCALE 0.12751743f
#define DEFER_THR 8.0f

typedef __attribute__((ext_vector_type(8))) __bf16 bf16x8;
typedef __attribute__((ext_vector_type(8))) unsigned short u16x8;
typedef __attribute__((ext_vector_type(4))) float f32x4;
typedef __attribute__((ext_vector_type(16))) float f32x16;
typedef __attribute__((ext_vector_type(4))) unsigned int u32x4;

static __device__ __forceinline__ unsigned short f2bf(float f) {
    unsigned int u = __builtin_bit_cast(unsigned int, f);
    u += 0x7fffu + ((u >> 16) & 1u);
    return (unsigned short)(u >> 16);
}

static __device__ __forceinline__ unsigned int cvtpk(float lo, float hi) {
    unsigned int r;
    asm("v_cvt_pk_bf16_f32 %0, %1, %2" : "=v"(r) : "v"(lo), "v"(hi));
    return r;
}

__global__ void k_cvt_kernel(const float* __restrict__ src,
                             unsigned short* __restrict__ dst, int n4) {
    int i = blockIdx.x * blockDim.x + threadIdx.x;
    if (i >= n4) return;
    float4 v = reinterpret_cast<const float4*>(src)[i];
    ushort4 o;
    o.x = f2bf(v.x); o.y = f2bf(v.y); o.z = f2bf(v.z); o.w = f2bf(v.w);
    reinterpret_cast<ushort4*>(dst)[i] = o;
}

__global__ void v_tr_kernel(const float* __restrict__ V,
                            unsigned short* __restrict__ Vt) {
    // 64x64 tile transpose through LDS. grid (S/64, D/64, B), 256 thr.
    __shared__ unsigned short T[64][72];
    const int k0 = blockIdx.x * 64;
    const int d0 = blockIdx.y * 64;
    const int b  = blockIdx.z;
    const int t  = threadIdx.x;
    const int r  = t >> 4;
    const int c4 = (t & 15) * 4;
#pragma unroll
    for (int rep = 0; rep < 4; ++rep) {
        int ki = rep * 16 + r;
        float4 v = *reinterpret_cast<const float4*>(
            &V[((size_t)(b * S_SZ + k0 + ki)) * D_SZ + d0 + c4]);
        T[ki][c4 + 0] = f2bf(v.x); T[ki][c4 + 1] = f2bf(v.y);
        T[ki][c4 + 2] = f2bf(v.z); T[ki][c4 + 3] = f2bf(v.w);
    }
    __syncthreads();
#pragma unroll
    for (int rep = 0; rep < 4; ++rep) {
        int di = rep * 16 + r;
        ushort4 o;
        o.x = T[c4 + 0][di]; o.y = T[c4 + 1][di];
        o.z = T[c4 + 2][di]; o.w = T[c4 + 3][di];
        *reinterpret_cast<ushort4*>(
            &Vt[((size_t)(b * D_SZ + d0 + di)) * S_SZ + k0 + c4]) = o;
    }
}

__global__ __launch_bounds__(256, 2) void mqa_fwd_kernel(
        const float* __restrict__ Q,
        const unsigned short* __restrict__ Kb,   // [B][S][D] bf16
        const unsigned short* __restrict__ Vt,   // [B][D][S] bf16
        float* __restrict__ Out)
{
    __shared__ __align__(16) unsigned short Kl[2][64 * 128];   // [key][d], swizzled
    __shared__ __align__(16) unsigned short Vl[3][128 * 64];   // [d][key], swizzled

    const int tid  = threadIdx.x;
    const int lane = tid & 63;
    const int w    = tid >> 6;
    const int l31  = lane & 31;   // q within wave; also A-frag row
    const int hi   = lane >> 5;   // k-half selector

    const int qt = blockIdx.x;
    const int h  = blockIdx.y;
    const int b  = blockIdx.z;

    // ---- staging lane constants (R6-proven mapping) ----
    const int krow = tid >> 4, kch = tid & 15;
    const int vdr  = tid >> 3, vch = tid & 7;
    int ksrc[4], kidx[4], vsrc[4], vidx[4];        // src: shorts; idx: bytes
#pragma unroll
    for (int j = 0; j < 4; ++j) {
        const int kr = krow + j * 16;
        ksrc[j] = kr * D_SZ + kch * 8;
        kidx[j] = kr * 256 + ((kch * 16) ^ ((kr & 7) << 4));
        const int dr = vdr + j * 32;
        vsrc[j] = dr * S_SZ + vch * 8;
        vidx[j] = dr * 128 + ((vch * 16) ^ ((dr & 7) << 4));
    }

    // ---- Q fragments (B-operand: col=q=l31, k=hi*8+i per 16-d chunk) ----
    const size_t qoff = (((size_t)b * H_SZ + h) * S_SZ + qt * QBLK + w * 32 + l31) * D_SZ;
    bf16x8 qf[8];
#pragma unroll
    for (int kc = 0; kc < 8; ++kc) {
        const float4 a = *reinterpret_cast<const float4*>(Q + qoff + kc * 16 + hi * 8);
        const float4 c = *reinterpret_cast<const float4*>(Q + qoff + kc * 16 + hi * 8 + 4);
        u16x8 u;
        u[0] = f2bf(a.x * QSCALE); u[1] = f2bf(a.y * QSCALE);
        u[2] = f2bf(a.z * QSCALE); u[3] = f2bf(a.w * QSCALE);
        u[4] = f2bf(c.x * QSCALE); u[5] = f2bf(c.y * QSCALE);
        u[6] = f2bf(c.z * QSCALE); u[7] = f2bf(c.w * QSCALE);
        qf[kc] = __builtin_bit_cast(bf16x8, u);
    }

    float m_s = -1e30f, l_s = 0.f;
    f32x16 oacc[4];   // oacc[db]: D[d = db*32 + (r&3)+8*(r>>2)+4*hi][q = l31]
#pragma unroll
    for (int n = 0; n < 4; ++n) {
#pragma unroll
        for (int r = 0; r < 16; ++r) oacc[n][r] = 0.f;
    }

    const unsigned short* KbB = Kb + (size_t)b * S_SZ * D_SZ;
    const unsigned short* VtB = Vt + (size_t)b * D_SZ * S_SZ;
    const int swz = (l31 & 7) << 4;

    // ---- prologue: stage tile 0 -> Kl[0], Vl[0] ----
    {
        u32x4 kr0[4], vr0[4];
#pragma unroll
        for (int j = 0; j < 4; ++j)
            kr0[j] = *reinterpret_cast<const u32x4*>(KbB + ksrc[j]);
#pragma unroll
        for (int j = 0; j < 4; ++j)
            vr0[j] = *reinterpret_cast<const u32x4*>(VtB + vsrc[j]);
#pragma unroll
        for (int j = 0; j < 4; ++j)
            *reinterpret_cast<u32x4*>((char*)Kl[0] + kidx[j]) = kr0[j];
#pragma unroll
        for (int j = 0; j < 4; ++j)
            *reinterpret_cast<u32x4*>((char*)Vl[0] + vidx[j]) = vr0[j];
    }

    // P fragments of the PREVIOUS tile (kept across iterations)
    bf16x8 PBp[4];
    u32x4 z4 = {0u, 0u, 0u, 0u};
#pragma unroll
    for (int n = 0; n < 4; ++n) PBp[n] = __builtin_bit_cast(bf16x8, z4);

    // rotating buffer indices: K read t&1; V read for PV(t-1) = vp; V write = vw
    int vp = 2, vw = 1;   // at t: vp=(t-1)%3 (valid t>=1), vw=(t+1)%3

    for (int t = 0; t < NT; ++t) {
        __syncthreads();  // buf writes of iter t-1 published; old reads done

        // ---- T14: issue tile t+1 global loads now; land after compute ----
        u32x4 kpre[4], vpre[4];
        const bool pf = (t + 1 < NT);
        if (pf) {
            const int k0n = (t + 1) * KBLK;
#pragma unroll
            for (int j = 0; j < 4; ++j)
                kpre[j] = *reinterpret_cast<const u32x4*>(KbB + k0n * D_SZ + ksrc[j]);
#pragma unroll
            for (int j = 0; j < 4; ++j)
                vpre[j] = *reinterpret_cast<const u32x4*>(VtB + k0n + vsrc[j]);
        }

        const char* Klc = (const char*)Kl[t & 1];

        // ---- QK^T(t): lane holds q=l31, keys kb*32 + (r&3)+8*(r>>2)+4*hi ----
        __builtin_amdgcn_s_setprio(1);
        f32x16 sacc[2];
#pragma unroll
        for (int kb = 0; kb < 2; ++kb) {
#pragma unroll
            for (int r = 0; r < 16; ++r) sacc[kb][r] = 0.f;
        }
#pragma unroll
        for (int kc = 0; kc < 8; ++kc) {
#pragma unroll
            for (int kb = 0; kb < 2; ++kb) {
                int off = (kb * 32 + l31) * 256 + ((kc * 32 + hi * 16) ^ swz);
                bf16x8 kf = *reinterpret_cast<const bf16x8*>(Klc + off);
                sacc[kb] = __builtin_amdgcn_mfma_f32_32x32x16_bf16(kf, qf[kc], sacc[kb], 0, 0, 0);
            }
        }

        // ---- PV(t-1): independent of sacc -> overlaps softmax below ----
        if (t > 0) {
            const char* Vpc = (const char*)Vl[vp];
#pragma unroll
            for (int kch2 = 0; kch2 < 4; ++kch2) {
#pragma unroll
                for (int db = 0; db < 4; ++db) {
                    int off = (db * 32 + l31) * 128 + ((kch2 * 32 + hi * 16) ^ swz);
                    bf16x8 vf = *reinterpret_cast<const bf16x8*>(Vpc + off);
                    oacc[db] = __builtin_amdgcn_mfma_f32_32x32x16_bf16(vf, PBp[kch2], oacc[db], 0, 0, 0);
                }
            }
        }
        __builtin_amdgcn_s_setprio(0);

        // ---- online softmax(t), one q-row per lane (lane^32 same q), log2 ----
        float mx = sacc[0][0];
#pragma unroll
        for (int kb = 0; kb < 2; ++kb) {
#pragma unroll
            for (int r = 0; r < 16; ++r) mx = fmaxf(mx, sacc[kb][r]);
        }
        mx = fmaxf(mx, __shfl_xor(mx, 32));
        if (!__all(mx <= m_s + DEFER_THR)) {
            const float mnew = fmaxf(m_s, mx);
            const float corr = exp2f(m_s - mnew);  // lane-local (q = l31)
            l_s *= corr;
            m_s = mnew;
#pragma unroll
            for (int n = 0; n < 4; ++n) {
#pragma unroll
                for (int r = 0; r < 16; ++r) oacc[n][r] *= corr;
            }
        }

        float rs = 0.f;
#pragma unroll
        for (int kb = 0; kb < 2; ++kb) {
#pragma unroll
            for (int r = 0; r < 16; ++r) {
                sacc[kb][r] = exp2f(sacc[kb][r] - m_s);
                rs += sacc[kb][r];
            }
            unsigned int a0 = cvtpk(sacc[kb][0],  sacc[kb][1]);
            unsigned int a1 = cvtpk(sacc[kb][2],  sacc[kb][3]);
            unsigned int a2 = cvtpk(sacc[kb][4],  sacc[kb][5]);
            unsigned int a3 = cvtpk(sacc[kb][6],  sacc[kb][7]);
            unsigned int a4 = cvtpk(sacc[kb][8],  sacc[kb][9]);
            unsigned int a5 = cvtpk(sacc[kb][10], sacc[kb][11]);
            unsigned int a6 = cvtpk(sacc[kb][12], sacc[kb][13]);
            unsigned int a7 = cvtpk(sacc[kb][14], sacc[kb][15]);
            asm("v_permlane32_swap_b32 %0, %1" : "+v"(a0), "+v"(a2));
            asm("v_permlane32_swap_b32 %0, %1" : "+v"(a1), "+v"(a3));
            asm("v_permlane32_swap_b32 %0, %1" : "+v"(a4), "+v"(a6));
            asm("v_permlane32_swap_b32 %0, %1" : "+v"(a5), "+v"(a7));
            u32x4 c0 = {a0, a1, a2, a3};
            u32x4 c1 = {a4, a5, a6, a7};
            PBp[kb * 2 + 0] = __builtin_bit_cast(bf16x8, c0);
            PBp[kb * 2 + 1] = __builtin_bit_cast(bf16x8, c1);
        }
        rs += __shfl_xor(rs, 32);
        l_s += rs;

        // ---- land the prefetch (visible after next barrier) ----
        if (pf) {
            char* Kn = (char*)Kl[(t + 1) & 1];
            char* Vn = (char*)Vl[vw];
#pragma unroll
            for (int j = 0; j < 4; ++j)
                *reinterpret_cast<u32x4*>(Kn + kidx[j]) = kpre[j];
#pragma unroll
            for (int j = 0; j < 4; ++j)
                *reinterpret_cast<u32x4*>(Vn + vidx[j]) = vpre[j];
        }
        vp = (vp == 2) ? 0 : vp + 1;
        vw = (vw == 2) ? 0 : vw + 1;
    }

    // ---- drain: PV(NT-1) ----
    {
        const char* Vpc = (const char*)Vl[vp];
#pragma unroll
        for (int kch2 = 0; kch2 < 4; ++kch2) {
#pragma unroll
            for (int db = 0; db < 4; ++db) {
                int off = (db * 32 + l31) * 128 + ((kch2 * 32 + hi * 16) ^ swz);
                bf16x8 vf = *reinterpret_cast<const bf16x8*>(Vpc + off);
                oacc[db] = __builtin_amdgcn_mfma_f32_32x32x16_bf16(vf, PBp[kch2], oacc[db], 0, 0, 0);
            }
        }
    }

    // ---- epilogue: O[q = l31][d] = oacc/l, 16 x float4 stores ----
    const float linv = 1.0f / l_s;
    float* obase = Out + (((size_t)b * H_SZ + h) * S_SZ + qt * QBLK + w * 32 + l31) * D_SZ;
#pragma unroll
    for (int db = 0; db < 4; ++db) {
#pragma unroll
        for (int rr = 0; rr < 4; ++rr) {
            f32x4 o;
            o[0] = oacc[db][rr * 4 + 0] * linv;
            o[1] = oacc[db][rr * 4 + 1] * linv;
            o[2] = oacc[db][rr * 4 + 2] * linv;
            o[3] = oacc[db][rr * 4 + 3] * linv;
            *reinterpret_cast<f32x4*>(obase + db * 32 + rr * 8 + hi * 4) = o;
        }
    }
}

extern "C" void kernel_launch(void* const* d_in, const int* in_sizes, int n_in,
                              void* d_out, int out_size, void* d_ws, size_t ws_size,
                              hipStream_t stream) {
    const float* Q = (const float*)d_in[0];
    const float* K = (const float*)d_in[1];
    const float* V = (const float*)d_in[2];
    float* Out = (float*)d_out;

    unsigned short* Kb = (unsigned short*)d_ws;
    unsigned short* Vt = Kb + (size_t)B_SZ * S_SZ * D_SZ;

    k_cvt_kernel<<<dim3((B_SZ * S_SZ * D_SZ / 4 + 255) / 256), dim3(256), 0, stream>>>(
        K, Kb, B_SZ * S_SZ * D_SZ / 4);
    v_tr_kernel<<<dim3(S_SZ / 64, D_SZ / 64, B_SZ), dim3(256), 0, stream>>>(V, Vt);
    mqa_fwd_kernel<<<dim3(S_SZ / QBLK, H_SZ, B_SZ), dim3(256), 0, stream>>>(Q, Kb, Vt, Out);
}